// Round 5
// baseline (2292.654 us; speedup 1.0000x reference)
//
#include <hip/hip_runtime.h>

#define N_NODES 100000
#define N_EDGES 1600000
#define D_IN    256
#define D_HID   64
#define D_OUT   40
#define PROP_N  16
#define HALF_BLOCKS 25000   // N_NODES / 4 rows-per-block

// ---- fp8 (OCP e4m3) helpers: HW convert, RNE, saturating ------------------
__device__ __forceinline__ float fp8_to_f32(int b) {
    return __builtin_amdgcn_cvt_f32_fp8(b, 0);
}
__device__ __forceinline__ unsigned char f32_to_fp8(float f) {
    int p = __builtin_amdgcn_cvt_pk_fp8_f32(f, f, 0, false);
    return (unsigned char)(p & 0xff);
}
__device__ __forceinline__ unsigned short f32x2_to_fp8x2(float a, float b) {
    int p = __builtin_amdgcn_cvt_pk_fp8_f32(a, b, 0, false);
    return (unsigned short)(p & 0xffff);
}

// ---------------------------------------------------------------------------
// Kernel 1: CSR row_ptr from sorted edge_row via binary search (lower_bound).
// ---------------------------------------------------------------------------
__global__ __launch_bounds__(256) void build_rowptr(const int* __restrict__ erow,
                                                    int* __restrict__ rp) {
    int r = blockIdx.x * blockDim.x + threadIdx.x;
    if (r > N_NODES) return;
    int lo = 0, hi = N_EDGES;
    while (lo < hi) {
        int mid = (lo + hi) >> 1;
        if (erow[mid] < r) lo = mid + 1; else hi = mid;
    }
    rp[r] = lo;
}

// ---------------------------------------------------------------------------
// Kernel 1b: pack (col, val) into int2 so the edge loop does one 8B load/edge.
// ---------------------------------------------------------------------------
__global__ __launch_bounds__(256) void pack_edges(const int* __restrict__ ecol,
                                                  const float* __restrict__ evalv,
                                                  int2* __restrict__ ep) {
    int i = blockIdx.x * blockDim.x + threadIdx.x;
    if (i >= N_EDGES) return;
    ep[i] = make_int2(ecol[i], __float_as_int(evalv[i]));
}

// ---------------------------------------------------------------------------
// Kernel 2: h = x @ W1 + b1 ; Y0f = h ; src = 0.5*diag*h ;
//           fp8 copy split into two half-dim arrays (3.2 MB each) for prop.
// ---------------------------------------------------------------------------
__global__ __launch_bounds__(256) void mlp1(const float* __restrict__ x,
                                            const float* __restrict__ W1,
                                            const float* __restrict__ b1,
                                            const float* __restrict__ diag,
                                            float* __restrict__ Y0f,
                                            unsigned char* __restrict__ Ylo,
                                            unsigned char* __restrict__ Yhi,
                                            float* __restrict__ src) {
    __shared__ float xs[32 * D_IN];  // 32 KB
    const int tid   = threadIdx.x;
    const int nbase = blockIdx.x * 32;

    {
        const float4* xv  = (const float4*)(x + (size_t)nbase * D_IN);
        float4*       xsv = (float4*)xs;
        #pragma unroll
        for (int i = 0; i < 8; ++i)
            xsv[tid + 256 * i] = xv[tid + 256 * i];
    }
    __syncthreads();

    const int dp = (tid & 31) * 2;   // dim pair
    const int ng = tid >> 5;         // node group 0..7 (4 nodes each)

    const float bx = b1[dp], by = b1[dp + 1];
    float a[4][2];
    #pragma unroll
    for (int i = 0; i < 4; ++i) { a[i][0] = bx; a[i][1] = by; }

    const float* xrow = xs + (size_t)(ng * 4) * D_IN;

    for (int k4 = 0; k4 < 64; ++k4) {
        const int k = k4 * 4;
        float2 w0 = *(const float2*)&W1[(k + 0) * 64 + dp];
        float2 w1 = *(const float2*)&W1[(k + 1) * 64 + dp];
        float2 w2 = *(const float2*)&W1[(k + 2) * 64 + dp];
        float2 w3 = *(const float2*)&W1[(k + 3) * 64 + dp];
        #pragma unroll
        for (int i = 0; i < 4; ++i) {
            float4 xq = *(const float4*)&xrow[i * D_IN + k];
            a[i][0] = fmaf(xq.x, w0.x, a[i][0]); a[i][1] = fmaf(xq.x, w0.y, a[i][1]);
            a[i][0] = fmaf(xq.y, w1.x, a[i][0]); a[i][1] = fmaf(xq.y, w1.y, a[i][1]);
            a[i][0] = fmaf(xq.z, w2.x, a[i][0]); a[i][1] = fmaf(xq.z, w2.y, a[i][1]);
            a[i][0] = fmaf(xq.w, w3.x, a[i][0]); a[i][1] = fmaf(xq.w, w3.y, a[i][1]);
        }
    }

    #pragma unroll
    for (int i = 0; i < 4; ++i) {
        const int n = nbase + ng * 4 + i;
        const float dg = diag[n];
        float2 h  = make_float2(a[i][0], a[i][1]);
        float2 sc = make_float2(0.5f * dg * h.x, 0.5f * dg * h.y);
        *(float2*)&Y0f[(size_t)n * 64 + dp] = h;
        *(float2*)&src[(size_t)n * 64 + dp] = sc;
        unsigned short pk = f32x2_to_fp8x2(h.x, h.y);
        if (dp < 32)
            *(unsigned short*)&Ylo[(size_t)n * 32 + dp] = pk;
        else
            *(unsigned short*)&Yhi[(size_t)n * 32 + (dp - 32)] = pk;
    }
}

// ---------------------------------------------------------------------------
// Kernel 3: one propagation step, feature-split into two half-dim passes
// within ONE dispatch. Blocks [0,25000) do dims 0-31 (gather Ylo, 3.2 MB);
// blocks [25000,50000) do dims 32-63 (gather Yhi). Each half-array fits a
// 4 MiB per-XCD L2, and blocks dispatch ~in order, so the gather working
// set stays L2-resident. All streaming traffic is non-temporal so it can't
// evict the gather set. Within a wave: lanes 0-31 take even edges, lanes
// 32-63 odd edges of the same row; combine with shfl_xor(32).
// ---------------------------------------------------------------------------
__global__ __launch_bounds__(256) void prop_step(
    const float* __restrict__ Yf,
    const unsigned char* __restrict__ Ylo,
    const unsigned char* __restrict__ Yhi,
    const float* __restrict__ src,
    float* __restrict__ Yof,
    unsigned char* __restrict__ Yolo,
    unsigned char* __restrict__ Yohi,
    const int* __restrict__ rp,
    const int2* __restrict__ ep) {

    const int hb   = (blockIdx.x >= HALF_BLOCKS) ? 1 : 0;
    const int bx   = blockIdx.x - hb * HALF_BLOCKS;
    const int w    = bx * 4 + (threadIdx.x >> 6);
    const int lane = threadIdx.x & 63;
    const int dl   = lane & 31;   // dim within the half
    const int eo   = lane >> 5;   // edge parity handled by this lane

    const unsigned char* __restrict__ Yin = hb ? Yhi : Ylo;

    int e0 = __builtin_amdgcn_readfirstlane(rp[w]);
    int e1 = __builtin_amdgcn_readfirstlane(rp[w + 1]);
    int npair = (e1 - e0 + 1) >> 1;

    const unsigned long long* epq = (const unsigned long long*)ep;

    float a0 = 0.f, a1 = 0.f, a2 = 0.f, a3 = 0.f;
    for (int p = 0; p < npair; p += 4) {
        int   ic0, ic1, ic2, ic3;
        float v0, v1, v2, v3;
        {
            int pe = p + 0, idx = e0 + 2 * pe + eo;
            bool ok = (pe < npair) && (idx < e1);
            unsigned long long pv = __builtin_nontemporal_load(&epq[ok ? idx : e0]);
            ic0 = (int)(unsigned int)pv;
            v0  = ok ? __uint_as_float((unsigned int)(pv >> 32)) : 0.f;
        }
        {
            int pe = p + 1, idx = e0 + 2 * pe + eo;
            bool ok = (pe < npair) && (idx < e1);
            unsigned long long pv = __builtin_nontemporal_load(&epq[ok ? idx : e0]);
            ic1 = (int)(unsigned int)pv;
            v1  = ok ? __uint_as_float((unsigned int)(pv >> 32)) : 0.f;
        }
        {
            int pe = p + 2, idx = e0 + 2 * pe + eo;
            bool ok = (pe < npair) && (idx < e1);
            unsigned long long pv = __builtin_nontemporal_load(&epq[ok ? idx : e0]);
            ic2 = (int)(unsigned int)pv;
            v2  = ok ? __uint_as_float((unsigned int)(pv >> 32)) : 0.f;
        }
        {
            int pe = p + 3, idx = e0 + 2 * pe + eo;
            bool ok = (pe < npair) && (idx < e1);
            unsigned long long pv = __builtin_nontemporal_load(&epq[ok ? idx : e0]);
            ic3 = (int)(unsigned int)pv;
            v3  = ok ? __uint_as_float((unsigned int)(pv >> 32)) : 0.f;
        }
        // 4 independent 32B-row gathers in flight (cached — NOT non-temporal)
        float y0 = fp8_to_f32(Yin[(size_t)ic0 * 32 + dl]);
        float y1 = fp8_to_f32(Yin[(size_t)ic1 * 32 + dl]);
        float y2 = fp8_to_f32(Yin[(size_t)ic2 * 32 + dl]);
        float y3 = fp8_to_f32(Yin[(size_t)ic3 * 32 + dl]);
        a0 = fmaf(v0, y0, a0);
        a1 = fmaf(v1, y1, a1);
        a2 = fmaf(v2, y2, a2);
        a3 = fmaf(v3, y3, a3);
    }

    float acc = (a0 + a1) + (a2 + a3);
    acc += __shfl_xor(acc, 32, 64);   // even-edge half + odd-edge half

    if (lane < 32) {
        const int d = hb * 32 + dl;
        const size_t idx = (size_t)w * 64 + d;
        float ys = __builtin_nontemporal_load(&Yf[idx]);
        float sv = __builtin_nontemporal_load(&src[idx]);
        float o  = fmaf(0.5f, ys, fmaf(0.5f, acc, sv));
        __builtin_nontemporal_store(o, &Yof[idx]);
        unsigned char* __restrict__ Yo = hb ? Yohi : Yolo;
        Yo[(size_t)w * 32 + dl] = f32_to_fp8(o);
    }
}

// ---------------------------------------------------------------------------
// Kernel 4: out = relu(Y) @ W2 + b2.  One node per thread, 40 accumulators.
// ---------------------------------------------------------------------------
__global__ __launch_bounds__(256) void mlp2(const float* __restrict__ Y,
                                            const float* __restrict__ W2,
                                            const float* __restrict__ b2,
                                            float* __restrict__ out) {
    __shared__ float W2s[D_HID * D_OUT];  // 10.2 KB
    __shared__ float b2s[D_OUT];
    int tid = threadIdx.x;
    for (int i = tid; i < D_HID * D_OUT; i += 256) W2s[i] = W2[i];
    if (tid < D_OUT) b2s[tid] = b2[tid];
    __syncthreads();

    int n = blockIdx.x * 256 + tid;
    if (n >= N_NODES) return;

    float acc[D_OUT];
    #pragma unroll
    for (int o = 0; o < D_OUT; ++o) acc[o] = b2s[o];

    const float4* Y4 = (const float4*)(Y + (size_t)n * 64);
    #pragma unroll 4
    for (int k4 = 0; k4 < 16; ++k4) {
        float4 y = Y4[k4];
        float ys[4];
        ys[0] = fmaxf(y.x, 0.0f); ys[1] = fmaxf(y.y, 0.0f);
        ys[2] = fmaxf(y.z, 0.0f); ys[3] = fmaxf(y.w, 0.0f);
        #pragma unroll
        for (int j = 0; j < 4; ++j) {
            int k = k4 * 4 + j;
            #pragma unroll
            for (int o = 0; o < D_OUT; ++o)
                acc[o] = fmaf(ys[j], W2s[k * D_OUT + o], acc[o]);
        }
    }

    float4* o4 = (float4*)(out + (size_t)n * D_OUT);  // 160 B row, 16B aligned
    #pragma unroll
    for (int q = 0; q < 10; ++q)
        o4[q] = make_float4(acc[4 * q], acc[4 * q + 1], acc[4 * q + 2], acc[4 * q + 3]);
}

// ---------------------------------------------------------------------------
extern "C" void kernel_launch(void* const* d_in, const int* in_sizes, int n_in,
                              void* d_out, int out_size, void* d_ws, size_t ws_size,
                              hipStream_t stream) {
    const float* x     = (const float*)d_in[0];
    const int*   erow  = (const int*)  d_in[1];
    const int*   ecol  = (const int*)  d_in[2];
    const float* evalv = (const float*)d_in[3];
    const float* diag  = (const float*)d_in[4];
    const float* W1    = (const float*)d_in[5];
    const float* b1    = (const float*)d_in[6];
    const float* W2    = (const float*)d_in[7];
    const float* b2    = (const float*)d_in[8];
    float* out = (float*)d_out;

    // workspace layout:
    //   Y0f, Y1f, src            : 3 x 25.6 MB fp32
    //   Y0lo, Y0hi, Y1lo, Y1hi   : 4 x 3.2 MB fp8 half-dim arrays
    //   ep                       : 12.8 MB int2
    //   rp                       : 0.4 MB
    const size_t NV = (size_t)N_NODES * D_HID;
    const size_t NH = (size_t)N_NODES * 32;
    float*         Y0f  = (float*)d_ws;
    float*         Y1f  = Y0f + NV;
    float*         src  = Y1f + NV;
    unsigned char* Y0lo = (unsigned char*)(src + NV);
    unsigned char* Y0hi = Y0lo + NH;
    unsigned char* Y1lo = Y0hi + NH;
    unsigned char* Y1hi = Y1lo + NH;
    int2*          ep   = (int2*)(Y1hi + NH);
    int*           rp   = (int*)(ep + N_EDGES);

    build_rowptr<<<(N_NODES + 1 + 255) / 256, 256, 0, stream>>>(erow, rp);
    pack_edges<<<(N_EDGES + 255) / 256, 256, 0, stream>>>(ecol, evalv, ep);
    mlp1<<<N_NODES / 32, 256, 0, stream>>>(x, W1, b1, diag, Y0f, Y0lo, Y0hi, src);

    float*         Yf[2]  = {Y0f, Y1f};
    unsigned char* Ylo[2] = {Y0lo, Y1lo};
    unsigned char* Yhi[2] = {Y0hi, Y1hi};
    for (int i = 0; i < PROP_N; ++i) {
        const int a = i & 1, b = (i + 1) & 1;
        prop_step<<<2 * HALF_BLOCKS, 256, 0, stream>>>(
            Yf[a], Ylo[a], Yhi[a], src, Yf[b], Ylo[b], Yhi[b], rp, ep);
    }
    // PROP_N even -> final fp32 result in Y0f
    mlp2<<<(N_NODES + 255) / 256, 256, 0, stream>>>(Y0f, W2, b2, out);
}

// Round 6
// 931.110 us; speedup vs baseline: 2.4623x; 2.4623x over previous
//
#include <hip/hip_runtime.h>

#define N_NODES 100000
#define N_EDGES 1600000
#define D_IN    256
#define D_HID   64
#define D_OUT   40
#define PROP_N  16

typedef short short8 __attribute__((ext_vector_type(8)));   // 8 bf16 (4 VGPRs)
typedef float f32x4  __attribute__((ext_vector_type(4)));   // MFMA accumulator

// ---- fp8 (OCP e4m3) helpers: HW convert, RNE, saturating ------------------
__device__ __forceinline__ float fp8_to_f32(int b) {
    return __builtin_amdgcn_cvt_f32_fp8(b, 0);
}
__device__ __forceinline__ unsigned char f32_to_fp8(float f) {
    int p = __builtin_amdgcn_cvt_pk_fp8_f32(f, f, 0, false);
    return (unsigned char)(p & 0xff);
}
// ---- bf16 helpers (RNE) ---------------------------------------------------
__device__ __forceinline__ unsigned short f32_to_bf16(float f) {
    unsigned int u = __float_as_uint(f);
    unsigned int r = (u + 0x7fffu + ((u >> 16) & 1u)) >> 16;
    return (unsigned short)r;
}
__device__ __forceinline__ unsigned int f32x2_to_bf16x2(float lo, float hi) {
    return (unsigned int)f32_to_bf16(lo) | ((unsigned int)f32_to_bf16(hi) << 16);
}

// ---------------------------------------------------------------------------
// Kernel 1: CSR row_ptr from sorted edge_row via binary search.
// ---------------------------------------------------------------------------
__global__ __launch_bounds__(256) void build_rowptr(const int* __restrict__ erow,
                                                    int* __restrict__ rp) {
    int r = blockIdx.x * blockDim.x + threadIdx.x;
    if (r > N_NODES) return;
    int lo = 0, hi = N_EDGES;
    while (lo < hi) {
        int mid = (lo + hi) >> 1;
        if (erow[mid] < r) lo = mid + 1; else hi = mid;
    }
    rp[r] = lo;
}

// ---------------------------------------------------------------------------
// Kernel 1b: pack (col, val) into int2 -> one 8B scalar load per edge.
// ---------------------------------------------------------------------------
__global__ __launch_bounds__(256) void pack_edges(const int* __restrict__ ecol,
                                                  const float* __restrict__ evalv,
                                                  int2* __restrict__ ep) {
    int i = blockIdx.x * blockDim.x + threadIdx.x;
    if (i >= N_EDGES) return;
    ep[i] = make_int2(ecol[i], __float_as_int(evalv[i]));
}

// ---------------------------------------------------------------------------
// Kernel 1c: W1 [256][64] fp32 -> W1T [64][256] bf16 (for MFMA B-fragments).
// ---------------------------------------------------------------------------
__global__ __launch_bounds__(256) void prep_w1t(const float* __restrict__ W1,
                                                unsigned short* __restrict__ W1T) {
    int i = blockIdx.x * 256 + threadIdx.x;           // 16384 elements
    if (i >= D_IN * D_HID) return;
    int k = i >> 6, n = i & 63;
    W1T[n * 256 + k] = f32_to_bf16(W1[i]);
}

// ---------------------------------------------------------------------------
// Kernel 2 (MFMA): h = x @ W1 + b1 ; Y0f = h ; Y08 = fp8(h) ; src = 0.5*diag*h
// Block = 256 thr (4 waves), M-tile = 64 rows (16/wave), N = 64 full.
// W1T staged in LDS padded to 264 shorts/row: b-frag ds_read_b128 is 2-way
// bank-aliased (free). A-fragments: stream x fp32, convert bf16 in-register.
// mfma_f32_16x16x32_bf16: A row m=lane&15, k=quad*8+j; B col n=lane&15,
// same k; D col=lane&15, row=quad*4+reg  [per cdna_hip_programming §3].
// ---------------------------------------------------------------------------
__global__ __launch_bounds__(256) void mlp1(const float* __restrict__ x,
                                            const unsigned short* __restrict__ W1T,
                                            const float* __restrict__ b1,
                                            const float* __restrict__ diag,
                                            float* __restrict__ Y0f,
                                            unsigned char* __restrict__ Y08,
                                            float* __restrict__ src) {
    __shared__ __align__(16) char W1s[64 * 528];   // 64 rows x 264 bf16 (pad +8)

    const int tid = threadIdx.x;

    // stage W1T -> LDS: thread t copies 128 B of row (t>>2), chunk (t&3)
    {
        const int r = tid >> 2, c = tid & 3;
        const float4* g = (const float4*)(W1T + r * 256 + c * 64);
        float4* l = (float4*)(W1s + r * 528 + c * 128);
        #pragma unroll
        for (int i = 0; i < 8; ++i) l[i] = g[i];
    }
    __syncthreads();

    const int wave  = tid >> 6;
    const int lane  = tid & 63;
    const int l15   = lane & 15;
    const int quad  = lane >> 4;
    const int mbase = blockIdx.x * 64 + wave * 16;

    f32x4 acc[4] = {};   // 4 col-tiles of 16

    const int m      = mbase + l15;
    const int m_safe = (m < N_NODES) ? m : 0;
    const float* xrow = x + (size_t)m_safe * D_IN + quad * 8;

    #pragma unroll
    for (int ks = 0; ks < 8; ++ks) {
        // A fragment: 8 consecutive fp32 -> 8 bf16
        float4 f0 = *(const float4*)(xrow + ks * 32);
        float4 f1 = *(const float4*)(xrow + ks * 32 + 4);
        union { short8 v; unsigned int u[4]; } a;
        a.u[0] = f32x2_to_bf16x2(f0.x, f0.y);
        a.u[1] = f32x2_to_bf16x2(f0.z, f0.w);
        a.u[2] = f32x2_to_bf16x2(f1.x, f1.y);
        a.u[3] = f32x2_to_bf16x2(f1.z, f1.w);

        #pragma unroll
        for (int ct = 0; ct < 4; ++ct) {
            const int n = ct * 16 + l15;
            short8 b = *(const short8*)(W1s + n * 528 + ks * 64 + quad * 16);
            acc[ct] = __builtin_amdgcn_mfma_f32_16x16x32_bf16(a.v, b, acc[ct], 0, 0, 0);
        }
    }

    // epilogue: bias, diag, three outputs
    float bias[4];
    #pragma unroll
    for (int ct = 0; ct < 4; ++ct) bias[ct] = b1[ct * 16 + l15];

    #pragma unroll
    for (int reg = 0; reg < 4; ++reg) {
        const int mr = mbase + quad * 4 + reg;
        if (mr >= N_NODES) continue;
        const float dg = diag[mr];
        #pragma unroll
        for (int ct = 0; ct < 4; ++ct) {
            const int col = ct * 16 + l15;
            const float h = acc[ct][reg] + bias[ct];
            const size_t idx = (size_t)mr * 64 + col;
            Y0f[idx] = h;
            src[idx] = 0.5f * dg * h;
            Y08[idx] = f32_to_fp8(h);
        }
    }
}

// ---------------------------------------------------------------------------
// Kernel 3: one propagation step (R4 structure — known-good).
// One wave per row, lane = feature dim; fp8 gather copy (64 B/row = 1 line,
// 1 request/edge — the request-rate floor); scalar edge loads; 8-wide unroll.
// ---------------------------------------------------------------------------
__global__ __launch_bounds__(256) void prop_step(const float* __restrict__ Yf,
                                                 const unsigned char* __restrict__ Y8,
                                                 const float* __restrict__ src,
                                                 float* __restrict__ Yof,
                                                 unsigned char* __restrict__ Yo8,
                                                 const int* __restrict__ rp,
                                                 const int2* __restrict__ ep) {
    int w    = blockIdx.x * (blockDim.x >> 6) + (threadIdx.x >> 6);
    int lane = threadIdx.x & 63;
    if (w >= N_NODES) return;

    int e0 = __builtin_amdgcn_readfirstlane(rp[w]);
    int e1 = __builtin_amdgcn_readfirstlane(rp[w + 1]);

    const size_t idx = (size_t)w * 64 + lane;
    float yself = Yf[idx];
    float sv    = src[idx];

    float a0 = 0.f, a1 = 0.f, a2 = 0.f, a3 = 0.f;
    float a4 = 0.f, a5 = 0.f, a6 = 0.f, a7 = 0.f;
    int e = e0;
    for (; e + 8 <= e1; e += 8) {
        int2 p0 = ep[e + 0], p1 = ep[e + 1], p2 = ep[e + 2], p3 = ep[e + 3];
        int2 p4 = ep[e + 4], p5 = ep[e + 5], p6 = ep[e + 6], p7 = ep[e + 7];
        int b0 = Y8[(size_t)p0.x * 64 + lane];
        int b1 = Y8[(size_t)p1.x * 64 + lane];
        int b2 = Y8[(size_t)p2.x * 64 + lane];
        int b3 = Y8[(size_t)p3.x * 64 + lane];
        int b4 = Y8[(size_t)p4.x * 64 + lane];
        int b5 = Y8[(size_t)p5.x * 64 + lane];
        int b6 = Y8[(size_t)p6.x * 64 + lane];
        int b7 = Y8[(size_t)p7.x * 64 + lane];
        a0 = fmaf(__int_as_float(p0.y), fp8_to_f32(b0), a0);
        a1 = fmaf(__int_as_float(p1.y), fp8_to_f32(b1), a1);
        a2 = fmaf(__int_as_float(p2.y), fp8_to_f32(b2), a2);
        a3 = fmaf(__int_as_float(p3.y), fp8_to_f32(b3), a3);
        a4 = fmaf(__int_as_float(p4.y), fp8_to_f32(b4), a4);
        a5 = fmaf(__int_as_float(p5.y), fp8_to_f32(b5), a5);
        a6 = fmaf(__int_as_float(p6.y), fp8_to_f32(b6), a6);
        a7 = fmaf(__int_as_float(p7.y), fp8_to_f32(b7), a7);
    }
    if (e + 4 <= e1) {
        int2 p0 = ep[e + 0], p1 = ep[e + 1], p2 = ep[e + 2], p3 = ep[e + 3];
        int b0 = Y8[(size_t)p0.x * 64 + lane];
        int b1 = Y8[(size_t)p1.x * 64 + lane];
        int b2 = Y8[(size_t)p2.x * 64 + lane];
        int b3 = Y8[(size_t)p3.x * 64 + lane];
        a0 = fmaf(__int_as_float(p0.y), fp8_to_f32(b0), a0);
        a1 = fmaf(__int_as_float(p1.y), fp8_to_f32(b1), a1);
        a2 = fmaf(__int_as_float(p2.y), fp8_to_f32(b2), a2);
        a3 = fmaf(__int_as_float(p3.y), fp8_to_f32(b3), a3);
        e += 4;
    }
    for (; e < e1; ++e) {
        int2 p = ep[e];
        a0 = fmaf(__int_as_float(p.y),
                  fp8_to_f32((int)Y8[(size_t)p.x * 64 + lane]), a0);
    }

    float acc = ((a0 + a1) + (a2 + a3)) + ((a4 + a5) + (a6 + a7));
    float o = fmaf(0.5f, yself, fmaf(0.5f, acc, sv));
    Yof[idx] = o;
    Yo8[idx] = f32_to_fp8(o);
}

// ---------------------------------------------------------------------------
// Kernel 4: out = relu(Y) @ W2 + b2.  One node per thread, 40 accumulators.
// ---------------------------------------------------------------------------
__global__ __launch_bounds__(256) void mlp2(const float* __restrict__ Y,
                                            const float* __restrict__ W2,
                                            const float* __restrict__ b2,
                                            float* __restrict__ out) {
    __shared__ float W2s[D_HID * D_OUT];
    __shared__ float b2s[D_OUT];
    int tid = threadIdx.x;
    for (int i = tid; i < D_HID * D_OUT; i += 256) W2s[i] = W2[i];
    if (tid < D_OUT) b2s[tid] = b2[tid];
    __syncthreads();

    int n = blockIdx.x * 256 + tid;
    if (n >= N_NODES) return;

    float acc[D_OUT];
    #pragma unroll
    for (int o = 0; o < D_OUT; ++o) acc[o] = b2s[o];

    const float4* Y4 = (const float4*)(Y + (size_t)n * 64);
    #pragma unroll 4
    for (int k4 = 0; k4 < 16; ++k4) {
        float4 y = Y4[k4];
        float ys[4];
        ys[0] = fmaxf(y.x, 0.0f); ys[1] = fmaxf(y.y, 0.0f);
        ys[2] = fmaxf(y.z, 0.0f); ys[3] = fmaxf(y.w, 0.0f);
        #pragma unroll
        for (int j = 0; j < 4; ++j) {
            int k = k4 * 4 + j;
            #pragma unroll
            for (int o = 0; o < D_OUT; ++o)
                acc[o] = fmaf(ys[j], W2s[k * D_OUT + o], acc[o]);
        }
    }

    float4* o4 = (float4*)(out + (size_t)n * D_OUT);
    #pragma unroll
    for (int q = 0; q < 10; ++q)
        o4[q] = make_float4(acc[4 * q], acc[4 * q + 1], acc[4 * q + 2], acc[4 * q + 3]);
}

// ---------------------------------------------------------------------------
extern "C" void kernel_launch(void* const* d_in, const int* in_sizes, int n_in,
                              void* d_out, int out_size, void* d_ws, size_t ws_size,
                              hipStream_t stream) {
    const float* x     = (const float*)d_in[0];
    const int*   erow  = (const int*)  d_in[1];
    const int*   ecol  = (const int*)  d_in[2];
    const float* evalv = (const float*)d_in[3];
    const float* diag  = (const float*)d_in[4];
    const float* W1    = (const float*)d_in[5];
    const float* b1    = (const float*)d_in[6];
    const float* W2    = (const float*)d_in[7];
    const float* b2    = (const float*)d_in[8];
    float* out = (float*)d_out;

    // workspace: Y0f|Y1f|src (fp32) | Y08|Y18 (fp8) | ep | rp | W1T
    const size_t NV = (size_t)N_NODES * D_HID;
    float*          Y0f = (float*)d_ws;
    float*          Y1f = Y0f + NV;
    float*          src = Y1f + NV;
    unsigned char*  Y08 = (unsigned char*)(src + NV);
    unsigned char*  Y18 = Y08 + NV;
    int2*           ep  = (int2*)(Y18 + NV);
    int*            rp  = (int*)(ep + N_EDGES);
    unsigned short* W1T = (unsigned short*)(rp + N_NODES + 1);

    build_rowptr<<<(N_NODES + 1 + 255) / 256, 256, 0, stream>>>(erow, rp);
    pack_edges<<<(N_EDGES + 255) / 256, 256, 0, stream>>>(ecol, evalv, ep);
    prep_w1t<<<(D_IN * D_HID + 255) / 256, 256, 0, stream>>>(W1, W1T);
    mlp1<<<(N_NODES + 63) / 64, 256, 0, stream>>>(x, W1T, b1, diag, Y0f, Y08, src);

    float*         Yf[2] = {Y0f, Y1f};
    unsigned char* Y8[2] = {Y08, Y18};
    for (int i = 0; i < PROP_N; ++i) {
        prop_step<<<(N_NODES + 3) / 4, 256, 0, stream>>>(
            Yf[i & 1], Y8[i & 1], src, Yf[(i + 1) & 1], Y8[(i + 1) & 1], rp, ep);
    }
    mlp2<<<(N_NODES + 255) / 256, 256, 0, stream>>>(Y0f, W2, b2, out);
}

// Round 8
// 924.563 us; speedup vs baseline: 2.4797x; 1.0071x over previous
//
#include <hip/hip_runtime.h>

#define N_NODES 100000
#define N_EDGES 1600000
#define D_IN    256
#define D_HID   64
#define D_OUT   40
#define PROP_N  16

typedef short short8 __attribute__((ext_vector_type(8)));   // 8 bf16 (4 VGPRs)
typedef float f32x4  __attribute__((ext_vector_type(4)));   // MFMA accumulator

// ---- fp8 (OCP e4m3) helpers: HW convert, RNE, saturating ------------------
__device__ __forceinline__ float fp8_to_f32(int b) {
    return __builtin_amdgcn_cvt_f32_fp8(b, 0);
}
__device__ __forceinline__ unsigned char f32_to_fp8(float f) {
    int p = __builtin_amdgcn_cvt_pk_fp8_f32(f, f, 0, false);
    return (unsigned char)(p & 0xff);
}
// ---- bf16 helpers (RNE) ---------------------------------------------------
__device__ __forceinline__ unsigned short f32_to_bf16(float f) {
    unsigned int u = __float_as_uint(f);
    unsigned int r = (u + 0x7fffu + ((u >> 16) & 1u)) >> 16;
    return (unsigned short)r;
}
__device__ __forceinline__ unsigned int f32x2_to_bf16x2(float lo, float hi) {
    return (unsigned int)f32_to_bf16(lo) | ((unsigned int)f32_to_bf16(hi) << 16);
}

// ---------------------------------------------------------------------------
// Kernel 1: CSR row_ptr from sorted edge_row via binary search.
// ---------------------------------------------------------------------------
__global__ __launch_bounds__(256) void build_rowptr(const int* __restrict__ erow,
                                                    int* __restrict__ rp) {
    int r = blockIdx.x * blockDim.x + threadIdx.x;
    if (r > N_NODES) return;
    int lo = 0, hi = N_EDGES;
    while (lo < hi) {
        int mid = (lo + hi) >> 1;
        if (erow[mid] < r) lo = mid + 1; else hi = mid;
    }
    rp[r] = lo;
}

// ---------------------------------------------------------------------------
// Kernel 1b: pack (col, val) into int2 -> one 8B scalar load per edge.
// ---------------------------------------------------------------------------
__global__ __launch_bounds__(256) void pack_edges(const int* __restrict__ ecol,
                                                  const float* __restrict__ evalv,
                                                  int2* __restrict__ ep) {
    int i = blockIdx.x * blockDim.x + threadIdx.x;
    if (i >= N_EDGES) return;
    ep[i] = make_int2(ecol[i], __float_as_int(evalv[i]));
}

// ---------------------------------------------------------------------------
// Kernel 1c: W1 [256][64] fp32 -> W1T [64][256] bf16 (for MFMA B-fragments).
// ---------------------------------------------------------------------------
__global__ __launch_bounds__(256) void prep_w1t(const float* __restrict__ W1,
                                                unsigned short* __restrict__ W1T) {
    int i = blockIdx.x * 256 + threadIdx.x;           // 16384 elements
    if (i >= D_IN * D_HID) return;
    int k = i >> 6, n = i & 63;
    W1T[n * 256 + k] = f32_to_bf16(W1[i]);
}

// ---------------------------------------------------------------------------
// Kernel 2 (MFMA, no LDS): h = x @ W1 + b1 ; Y0f = h ; Y08 = fp8(h) ;
//   src = 0.5*diag*h          (outputs byte-identical to the R6 version)
// One wave per block, M=16 rows, grid 6250 -> ~24 waves/CU: no LDS
// occupancy cap, no bank conflicts, no grid starvation. B-fragments read
// straight from W1T in global: 32 KB shared by all blocks -> L2-resident.
// mfma_f32_16x16x32_bf16: A row m=lane&15, k=quad*8+j; B col n=lane&15;
// D col=lane&15, row=quad*4+reg.
// ---------------------------------------------------------------------------
__global__ __launch_bounds__(64) void mlp1(const float* __restrict__ x,
                                           const unsigned short* __restrict__ W1T,
                                           const float* __restrict__ b1,
                                           const float* __restrict__ diag,
                                           float* __restrict__ Y0f,
                                           unsigned char* __restrict__ Y08,
                                           float* __restrict__ src) {
    const int lane  = threadIdx.x;
    const int l15   = lane & 15;
    const int quad  = lane >> 4;
    const int mbase = blockIdx.x * 16;      // 6250 * 16 == 100000 exactly

    f32x4 acc[4] = {};
    const float* xrow = x + (size_t)(mbase + l15) * D_IN + quad * 8;

    #pragma unroll
    for (int ks = 0; ks < 8; ++ks) {
        float4 f0 = *(const float4*)(xrow + ks * 32);
        float4 f1 = *(const float4*)(xrow + ks * 32 + 4);
        union { short8 v; unsigned int u[4]; } a;
        a.u[0] = f32x2_to_bf16x2(f0.x, f0.y);
        a.u[1] = f32x2_to_bf16x2(f0.z, f0.w);
        a.u[2] = f32x2_to_bf16x2(f1.x, f1.y);
        a.u[3] = f32x2_to_bf16x2(f1.z, f1.w);

        #pragma unroll
        for (int ct = 0; ct < 4; ++ct) {
            short8 b = *(const short8*)(W1T + (ct * 16 + l15) * 256 + ks * 32 + quad * 8);
            acc[ct] = __builtin_amdgcn_mfma_f32_16x16x32_bf16(a.v, b, acc[ct], 0, 0, 0);
        }
    }

    float bias[4];
    #pragma unroll
    for (int ct = 0; ct < 4; ++ct) bias[ct] = b1[ct * 16 + l15];

    #pragma unroll
    for (int reg = 0; reg < 4; ++reg) {
        const int mr = mbase + quad * 4 + reg;
        const float dg = diag[mr];
        #pragma unroll
        for (int ct = 0; ct < 4; ++ct) {
            const int col = ct * 16 + l15;
            const float h = acc[ct][reg] + bias[ct];
            const size_t idx = (size_t)mr * 64 + col;
            Y0f[idx] = h;
            src[idx] = 0.5f * dg * h;
            Y08[idx] = f32_to_fp8(h);
        }
    }
}

// ---------------------------------------------------------------------------
// Kernel 3: one propagation step (R4/R6 structure — known-good).
// One wave per row, lane = feature dim; fp8 gather copy (64 B/row = 1 line,
// 1 request/edge — the request-rate floor); scalar edge loads; 8-wide unroll.
// ---------------------------------------------------------------------------
__global__ __launch_bounds__(256) void prop_step(const float* __restrict__ Yf,
                                                 const unsigned char* __restrict__ Y8,
                                                 const float* __restrict__ src,
                                                 float* __restrict__ Yof,
                                                 unsigned char* __restrict__ Yo8,
                                                 const int* __restrict__ rp,
                                                 const int2* __restrict__ ep) {
    int w    = blockIdx.x * (blockDim.x >> 6) + (threadIdx.x >> 6);
    int lane = threadIdx.x & 63;
    if (w >= N_NODES) return;

    int e0 = __builtin_amdgcn_readfirstlane(rp[w]);
    int e1 = __builtin_amdgcn_readfirstlane(rp[w + 1]);

    const size_t idx = (size_t)w * 64 + lane;
    float yself = Yf[idx];
    float sv    = src[idx];

    float a0 = 0.f, a1 = 0.f, a2 = 0.f, a3 = 0.f;
    float a4 = 0.f, a5 = 0.f, a6 = 0.f, a7 = 0.f;
    int e = e0;
    for (; e + 8 <= e1; e += 8) {
        int2 p0 = ep[e + 0], p1 = ep[e + 1], p2 = ep[e + 2], p3 = ep[e + 3];
        int2 p4 = ep[e + 4], p5 = ep[e + 5], p6 = ep[e + 6], p7 = ep[e + 7];
        int b0 = Y8[(size_t)p0.x * 64 + lane];
        int b1 = Y8[(size_t)p1.x * 64 + lane];
        int b2 = Y8[(size_t)p2.x * 64 + lane];
        int b3 = Y8[(size_t)p3.x * 64 + lane];
        int b4 = Y8[(size_t)p4.x * 64 + lane];
        int b5 = Y8[(size_t)p5.x * 64 + lane];
        int b6 = Y8[(size_t)p6.x * 64 + lane];
        int b7 = Y8[(size_t)p7.x * 64 + lane];
        a0 = fmaf(__int_as_float(p0.y), fp8_to_f32(b0), a0);
        a1 = fmaf(__int_as_float(p1.y), fp8_to_f32(b1), a1);
        a2 = fmaf(__int_as_float(p2.y), fp8_to_f32(b2), a2);
        a3 = fmaf(__int_as_float(p3.y), fp8_to_f32(b3), a3);
        a4 = fmaf(__int_as_float(p4.y), fp8_to_f32(b4), a4);
        a5 = fmaf(__int_as_float(p5.y), fp8_to_f32(b5), a5);
        a6 = fmaf(__int_as_float(p6.y), fp8_to_f32(b6), a6);
        a7 = fmaf(__int_as_float(p7.y), fp8_to_f32(b7), a7);
    }
    if (e + 4 <= e1) {
        int2 p0 = ep[e + 0], p1 = ep[e + 1], p2 = ep[e + 2], p3 = ep[e + 3];
        int b0 = Y8[(size_t)p0.x * 64 + lane];
        int b1 = Y8[(size_t)p1.x * 64 + lane];
        int b2 = Y8[(size_t)p2.x * 64 + lane];
        int b3 = Y8[(size_t)p3.x * 64 + lane];
        a0 = fmaf(__int_as_float(p0.y), fp8_to_f32(b0), a0);
        a1 = fmaf(__int_as_float(p1.y), fp8_to_f32(b1), a1);
        a2 = fmaf(__int_as_float(p2.y), fp8_to_f32(b2), a2);
        a3 = fmaf(__int_as_float(p3.y), fp8_to_f32(b3), a3);
        e += 4;
    }
    for (; e < e1; ++e) {
        int2 p = ep[e];
        a0 = fmaf(__int_as_float(p.y),
                  fp8_to_f32((int)Y8[(size_t)p.x * 64 + lane]), a0);
    }

    float acc = ((a0 + a1) + (a2 + a3)) + ((a4 + a5) + (a6 + a7));
    float o = fmaf(0.5f, yself, fmaf(0.5f, acc, sv));
    Yof[idx] = o;
    Yo8[idx] = f32_to_fp8(o);
}

// ---------------------------------------------------------------------------
// Kernel 4: out = relu(Y) @ W2 + b2.  One node per thread, 40 accumulators.
// ---------------------------------------------------------------------------
__global__ __launch_bounds__(256) void mlp2(const float* __restrict__ Y,
                                            const float* __restrict__ W2,
                                            const float* __restrict__ b2,
                                            float* __restrict__ out) {
    __shared__ float W2s[D_HID * D_OUT];
    __shared__ float b2s[D_OUT];
    int tid = threadIdx.x;
    for (int i = tid; i < D_HID * D_OUT; i += 256) W2s[i] = W2[i];
    if (tid < D_OUT) b2s[tid] = b2[tid];
    __syncthreads();

    int n = blockIdx.x * 256 + tid;
    if (n >= N_NODES) return;

    float acc[D_OUT];
    #pragma unroll
    for (int o = 0; o < D_OUT; ++o) acc[o] = b2s[o];

    const float4* Y4 = (const float4*)(Y + (size_t)n * 64);
    #pragma unroll 4
    for (int k4 = 0; k4 < 16; ++k4) {
        float4 y = Y4[k4];
        float ys[4];
        ys[0] = fmaxf(y.x, 0.0f); ys[1] = fmaxf(y.y, 0.0f);
        ys[2] = fmaxf(y.z, 0.0f); ys[3] = fmaxf(y.w, 0.0f);
        #pragma unroll
        for (int j = 0; j < 4; ++j) {
            int k = k4 * 4 + j;
            #pragma unroll
            for (int o = 0; o < D_OUT; ++o)
                acc[o] = fmaf(ys[j], W2s[k * D_OUT + o], acc[o]);
        }
    }

    float4* o4 = (float4*)(out + (size_t)n * D_OUT);
    #pragma unroll
    for (int q = 0; q < 10; ++q)
        o4[q] = make_float4(acc[4 * q], acc[4 * q + 1], acc[4 * q + 2], acc[4 * q + 3]);
}

// ---------------------------------------------------------------------------
extern "C" void kernel_launch(void* const* d_in, const int* in_sizes, int n_in,
                              void* d_out, int out_size, void* d_ws, size_t ws_size,
                              hipStream_t stream) {
    const float* x     = (const float*)d_in[0];
    const int*   erow  = (const int*)  d_in[1];
    const int*   ecol  = (const int*)  d_in[2];
    const float* evalv = (const float*)d_in[3];
    const float* diag  = (const float*)d_in[4];
    const float* W1    = (const float*)d_in[5];
    const float* b1    = (const float*)d_in[6];
    const float* W2    = (const float*)d_in[7];
    const float* b2    = (const float*)d_in[8];
    float* out = (float*)d_out;

    // workspace: Y0f|Y1f|src (fp32) | Y08|Y18 (fp8) | ep | rp | W1T
    // (layout identical to R6)
    const size_t NV = (size_t)N_NODES * D_HID;
    float*          Y0f = (float*)d_ws;
    float*          Y1f = Y0f + NV;
    float*          src = Y1f + NV;
    unsigned char*  Y08 = (unsigned char*)(src + NV);
    unsigned char*  Y18 = Y08 + NV;
    int2*           ep  = (int2*)(Y18 + NV);
    int*            rp  = (int*)(ep + N_EDGES);
    unsigned short* W1T = (unsigned short*)(rp + N_NODES + 1);

    build_rowptr<<<(N_NODES + 1 + 255) / 256, 256, 0, stream>>>(erow, rp);
    pack_edges<<<(N_EDGES + 255) / 256, 256, 0, stream>>>(ecol, evalv, ep);
    prep_w1t<<<(D_IN * D_HID + 255) / 256, 256, 0, stream>>>(W1, W1T);
    mlp1<<<N_NODES / 16, 64, 0, stream>>>(x, W1T, b1, diag, Y0f, Y08, src);

    float*         Yf[2] = {Y0f, Y1f};
    unsigned char* Y8[2] = {Y08, Y18};
    for (int i = 0; i < PROP_N; ++i) {
        prop_step<<<(N_NODES + 3) / 4, 256, 0, stream>>>(
            Yf[i & 1], Y8[i & 1], src, Yf[(i + 1) & 1], Y8[(i + 1) & 1], rp, ep);
    }
    // PROP_N even -> final fp32 result in Y0f
    mlp2<<<(N_NODES + 255) / 256, 256, 0, stream>>>(Y0f, W2, b2, out);
}